// Round 2
// baseline (521.833 us; speedup 1.0000x reference)
//
#include <hip/hip_runtime.h>

typedef _Float16 f16;
typedef _Float16 f16x8 __attribute__((ext_vector_type(8)));
typedef _Float16 f16x4v __attribute__((ext_vector_type(4)));
typedef float f32x4 __attribute__((ext_vector_type(4)));

#define DEVINL __device__ __forceinline__

DEVINL void gload16(const void* g, void* l) {
  __builtin_amdgcn_global_load_lds(
      (const __attribute__((address_space(1))) void*)g,
      (__attribute__((address_space(3))) void*)l, 16, 0, 0);
}

// ---------------------------------------------------------------------------
// weff2: WT[n][k] = (W[k][n] + la[k][:]·lb[:][n]) * (n<scaleCols ? 0.125 : 1)
// tile 256n x 64k, 256 threads. lb column in VGPRs, la rows via block-uniform
// (scalar) loads, transpose through a swizzled LDS tile for coalesced writes.
// ---------------------------------------------------------------------------
__global__ __launch_bounds__(256) void weff2(
    const float* __restrict__ W, const float* __restrict__ la,
    const float* __restrict__ lb, f16* __restrict__ WT,
    int N, int K, int scaleCols)
{
  __shared__ __align__(16) f16 Ts[256 * 64];
  int t = threadIdx.x;
  int n0 = blockIdx.x * 256, k0 = blockIdx.y * 64;
  float scale = (n0 < scaleCols) ? 0.125f : 1.0f;
  float lbr[32];
  #pragma unroll
  for (int r = 0; r < 32; ++r) lbr[r] = lb[(size_t)r * N + n0 + t];
  #pragma unroll
  for (int c = 0; c < 8; ++c) {
    float acc[8];
    #pragma unroll
    for (int j = 0; j < 8; ++j)
      acc[j] = W[(size_t)(k0 + c * 8 + j) * N + n0 + t];
    #pragma unroll
    for (int j = 0; j < 8; ++j)
      #pragma unroll
      for (int r = 0; r < 32; ++r)
        acc[j] += la[(size_t)(k0 + c * 8 + j) * 32 + r] * lbr[r];
    f16x8 h;
    #pragma unroll
    for (int j = 0; j < 8; ++j) h[j] = (f16)(acc[j] * scale);
    *(f16x8*)(Ts + t * 64 + ((c ^ (t & 7)) * 8)) = h;
  }
  __syncthreads();
  #pragma unroll
  for (int it = 0; it < 8; ++it) {
    int id = it * 256 + t;
    int row = id >> 3, c = id & 7;
    f16x8 h = *(const f16x8*)(Ts + row * 64 + ((c ^ (row & 7)) * 8));
    *(f16x8*)(WT + (size_t)(n0 + row) * K + k0 + c * 8) = h;
  }
}

// ---------------------------------------------------------------------------
__global__ __launch_bounds__(256) void cvt_f32_f16(const float* __restrict__ in,
                                                   f16* __restrict__ out)
{
  int i = (blockIdx.x * 256 + threadIdx.x) * 4;
  float4 v = *(const float4*)(in + i);
  f16x4v o = {(f16)v.x, (f16)v.y, (f16)v.z, (f16)v.w};
  *(f16x4v*)(out + i) = o;
}

// ---------------------------------------------------------------------------
__global__ __launch_bounds__(256) void mask_canon(const unsigned char* __restrict__ m,
                                                  unsigned char* __restrict__ out)
{
  __shared__ int flag;
  if (threadIdx.x == 0) flag = 0;
  __syncthreads();
  int found = 0;
  for (int p = threadIdx.x; p < 12288; p += 256)
    if ((p & 3) && m[p]) found = 1;
  if (found) flag = 1;
  __syncthreads();
  int u8 = flag;
  const int* mi = (const int*)m;
  for (int idx = threadIdx.x; idx < 4096; idx += 256) {
    int b = idx >> 9, k = idx & 511;
    int v = u8 ? (int)m[b * 1536 + k] : mi[b * 1536 + k];
    out[idx] = (unsigned char)(v != 0);
  }
}

// ---------------------------------------------------------------------------
// 128x128 GEMM, BK=64, 4 waves (2x2 of 64x64), mfma_f32_16x16x32_f16.
// LDS rows 128B, XOR-swizzled (chunk ^= row&7) via pre-swizzled global source
// (global_load_lds dest must stay linear) + swizzled ds_read. XCD block remap.
// ---------------------------------------------------------------------------
template <int EPI>
__global__ __launch_bounds__(256) void gemm128(
    const f16* __restrict__ A, const f16* __restrict__ Bt,
    int M, int N, int K,
    const float* __restrict__ bias, const f16* __restrict__ resid,
    f16* __restrict__ outH, float* __restrict__ outF,
    f16* __restrict__ Qo, f16* __restrict__ Ko, f16* __restrict__ Vto)
{
  __shared__ __align__(16) f16 As[128 * 64];
  __shared__ __align__(16) f16 Bs[128 * 64];
  int tid = threadIdx.x, wid = tid >> 6, l = tid & 63;
  int lg = l >> 4, lr = l & 15;
  int nbx = gridDim.x;
  int nwg = nbx * gridDim.y;
  int flat = blockIdx.y * nbx + blockIdx.x;
  flat = (flat & 7) * (nwg >> 3) + (flat >> 3);   // XCD-contiguous tiles
  int bm = (flat % nbx) * 128, bn = (flat / nbx) * 128;
  int wr = (wid >> 1) * 64, wc = (wid & 1) * 64;
  f32x4 acc[4][4] = {};

  int srow = l >> 3, scol = l & 7;
  int sc8 = (scol ^ srow) * 8;                    // pre-swizzled source chunk
  const f16* gA = A + (size_t)(bm + wid * 32 + srow) * K + sc8;
  const f16* gB = Bt + (size_t)(bn + wid * 32 + srow) * K + sc8;
  f16* lA = As + wid * 32 * 64;
  f16* lB = Bs + wid * 32 * 64;

  for (int k0 = 0; k0 < K; k0 += 64) {
    __syncthreads();
    #pragma unroll
    for (int is = 0; is < 4; ++is) {
      gload16(gA + (size_t)(is * 8) * K + k0, lA + is * 8 * 64);
      gload16(gB + (size_t)(is * 8) * K + k0, lB + is * 8 * 64);
    }
    __syncthreads();
    f16x8 af[2][4], bf[2][4];
    int x = lr & 7;
    #pragma unroll
    for (int i = 0; i < 4; ++i) {
      int row = wr + i * 16 + lr;
      af[0][i] = *(const f16x8*)(As + row * 64 + ((lg ^ x) * 8));
      af[1][i] = *(const f16x8*)(As + row * 64 + (((4 + lg) ^ x) * 8));
    }
    #pragma unroll
    for (int j = 0; j < 4; ++j) {
      int row = wc + j * 16 + lr;
      bf[0][j] = *(const f16x8*)(Bs + row * 64 + ((lg ^ x) * 8));
      bf[1][j] = *(const f16x8*)(Bs + row * 64 + (((4 + lg) ^ x) * 8));
    }
    #pragma unroll
    for (int kk = 0; kk < 2; ++kk)
      #pragma unroll
      for (int i = 0; i < 4; ++i)
        #pragma unroll
        for (int j = 0; j < 4; ++j)
          acc[i][j] = __builtin_amdgcn_mfma_f32_16x16x32_f16(af[kk][i], bf[kk][j], acc[i][j], 0, 0, 0);
  }

  #pragma unroll
  for (int i = 0; i < 4; ++i) {
    #pragma unroll
    for (int j = 0; j < 4; ++j) {
      int n = bn + wc + j * 16 + lr;
      float bv = (EPI >= 1) ? bias[n] : 0.0f;
      #pragma unroll
      for (int r = 0; r < 4; ++r) {
        int m = bm + wr + i * 16 + lg * 4 + r;
        float v = acc[i][j][r];
        if (EPI == 0) {
          int bb = m >> 9, ss = m & 511;
          int which = n >> 10, c = n & 1023, hh = c >> 6, dd = c & 63;
          size_t base = (size_t)(bb * 16 + hh);
          if (which == 0)      Qo[(base * 512 + ss) * 64 + dd] = (f16)v;
          else if (which == 1) Ko[(base * 512 + ss) * 64 + dd] = (f16)v;
          else                 Vto[(base * 64 + dd) * 512 + ss] = (f16)v;
        } else if (EPI == 1) {
          v += bv;
          v = 0.5f * v * (1.0f + erff(v * 0.70710678118654752f));
          outH[(size_t)m * N + n] = (f16)v;
        } else if (EPI == 2) {
          v += bv + (float)resid[(size_t)m * N + n];
          outH[(size_t)m * N + n] = (f16)v;
        } else {
          outF[(size_t)m * N + n] = v + bv;
        }
      }
    }
  }
}

// ---------------------------------------------------------------------------
// Flash attention, 4 waves x 32 q-rows, K/V tiles of 128 in LDS.
// All LDS buffers XOR-swizzled: Ks/Vs via pre-swizzled global_load_lds source,
// Ps (VALU-written) swizzled on both sides. XCD remap groups qblks per bh.
// ---------------------------------------------------------------------------
__global__ __launch_bounds__(256) void attn_kernel(
    const f16* __restrict__ Q, const f16* __restrict__ Kc,
    const f16* __restrict__ Vt, const unsigned char* __restrict__ cmask,
    f16* __restrict__ XO)
{
  __shared__ __align__(16) f16 Ks[128 * 64];     // [krow][d]  rows 128B
  __shared__ __align__(16) f16 Vs[64 * 128];     // [d][krow]  rows 256B
  __shared__ __align__(16) f16 Ps[4 * 32 * 128]; // per-wave P rows 256B
  int tid = threadIdx.x, w = tid >> 6, l = tid & 63;
  int lg = l >> 4, lr = l & 15;
  int flat = blockIdx.y * 4 + blockIdx.x;
  flat = (flat & 7) * 64 + (flat >> 3);          // 512 blocks, XCD-contiguous
  int qblk = flat & 3, bh = flat >> 2;
  int b = bh >> 4, h = bh & 15;
  const f16* Qg = Q + (size_t)bh * 512 * 64 + qblk * 128 * 64;
  const f16* Kg = Kc + (size_t)bh * 512 * 64;
  const f16* Vg = Vt + (size_t)bh * 64 * 512;
  const unsigned char* mb = cmask + b * 512;

  f16x8 qf[2][2];
  #pragma unroll
  for (int i = 0; i < 2; ++i)
    #pragma unroll
    for (int kc = 0; kc < 2; ++kc)
      qf[i][kc] = *(const f16x8*)(Qg + (size_t)(w * 32 + i * 16 + lr) * 64 + kc * 32 + lg * 8);

  f32x4 O[2][4] = {};
  float mrow[2][4], lrow[2][4];
  #pragma unroll
  for (int i = 0; i < 2; ++i)
    #pragma unroll
    for (int r = 0; r < 4; ++r) { mrow[i][r] = -1e30f; lrow[i][r] = 0.0f; }

  f16* Pw = Ps + w * 32 * 128;
  int ksrow = l >> 3;                     // K staging: 8 rows/instr
  int ksc = ((l & 7) ^ ksrow) * 8;        // pre-swizzled source chunk
  int vrow = l >> 4;                      // V staging: 4 rows/instr
  int v7 = (w * 4 + vrow) & 7;
  int vsc = ((l & 15) ^ v7) * 8;

  for (int kt = 0; kt < 4; ++kt) {
    __syncthreads();
    #pragma unroll
    for (int is = 0; is < 4; ++is)
      gload16(Kg + (size_t)(kt * 128 + is * 32 + w * 8 + ksrow) * 64 + ksc,
              Ks + (is * 32 + w * 8) * 64);
    #pragma unroll
    for (int is = 0; is < 4; ++is)
      gload16(Vg + (size_t)(is * 16 + w * 4 + vrow) * 512 + kt * 128 + vsc,
              Vs + (is * 16 + w * 4) * 128);
    __syncthreads();

    int x = lr & 7;
    f32x4 sc[2][8] = {};
    #pragma unroll
    for (int j = 0; j < 8; ++j) {
      const f16* krow = Ks + (j * 16 + lr) * 64;
      f16x8 kf0 = *(const f16x8*)(krow + ((lg ^ x) * 8));
      f16x8 kf1 = *(const f16x8*)(krow + (((4 + lg) ^ x) * 8));
      sc[0][j] = __builtin_amdgcn_mfma_f32_16x16x32_f16(qf[0][0], kf0, sc[0][j], 0, 0, 0);
      sc[0][j] = __builtin_amdgcn_mfma_f32_16x16x32_f16(qf[0][1], kf1, sc[0][j], 0, 0, 0);
      sc[1][j] = __builtin_amdgcn_mfma_f32_16x16x32_f16(qf[1][0], kf0, sc[1][j], 0, 0, 0);
      sc[1][j] = __builtin_amdgcn_mfma_f32_16x16x32_f16(qf[1][1], kf1, sc[1][j], 0, 0, 0);
    }
    bool keep[8];
    #pragma unroll
    for (int j = 0; j < 8; ++j) keep[j] = mb[kt * 128 + j * 16 + lr] != 0;
    #pragma unroll
    for (int i = 0; i < 2; ++i)
      #pragma unroll
      for (int j = 0; j < 8; ++j)
        #pragma unroll
        for (int r = 0; r < 4; ++r)
          sc[i][j][r] = keep[j] ? sc[i][j][r] : -1e30f;

    #pragma unroll
    for (int i = 0; i < 2; ++i) {
      #pragma unroll
      for (int r = 0; r < 4; ++r) {
        float pm = sc[i][0][r];
        #pragma unroll
        for (int j = 1; j < 8; ++j) pm = fmaxf(pm, sc[i][j][r]);
        pm = fmaxf(pm, __shfl_xor(pm, 1));
        pm = fmaxf(pm, __shfl_xor(pm, 2));
        pm = fmaxf(pm, __shfl_xor(pm, 4));
        pm = fmaxf(pm, __shfl_xor(pm, 8));
        float mn = fmaxf(mrow[i][r], pm);
        float alpha = __expf(mrow[i][r] - mn);
        mrow[i][r] = mn;
        lrow[i][r] *= alpha;
        #pragma unroll
        for (int jd = 0; jd < 4; ++jd) O[i][jd][r] *= alpha;
      }
    }
    #pragma unroll
    for (int i = 0; i < 2; ++i) {
      float rs[4] = {0.f, 0.f, 0.f, 0.f};
      #pragma unroll
      for (int j = 0; j < 8; ++j)
        #pragma unroll
        for (int r = 0; r < 4; ++r) {
          float p = __expf(sc[i][j][r] - mrow[i][r]);
          rs[r] += p;
          int prow = i * 16 + lg * 4 + r;
          int pc = j * 16 + lr;
          Pw[prow * 128 + ((((pc >> 3) ^ (prow & 7)) << 3) | (pc & 7))] = (f16)p;
        }
      #pragma unroll
      for (int r = 0; r < 4; ++r) {
        float s = rs[r];
        s += __shfl_xor(s, 1); s += __shfl_xor(s, 2);
        s += __shfl_xor(s, 4); s += __shfl_xor(s, 8);
        lrow[i][r] += s;
      }
    }
    #pragma unroll
    for (int kk = 0; kk < 4; ++kk) {
      int c0 = ((kk * 4 + lg) ^ x) * 8;
      f16x8 pa0 = *(const f16x8*)(Pw + lr * 128 + c0);
      f16x8 pa1 = *(const f16x8*)(Pw + (16 + lr) * 128 + c0);
      #pragma unroll
      for (int jd = 0; jd < 4; ++jd) {
        f16x8 vb = *(const f16x8*)(Vs + (jd * 16 + lr) * 128 + c0);
        O[0][jd] = __builtin_amdgcn_mfma_f32_16x16x32_f16(pa0, vb, O[0][jd], 0, 0, 0);
        O[1][jd] = __builtin_amdgcn_mfma_f32_16x16x32_f16(pa1, vb, O[1][jd], 0, 0, 0);
      }
    }
  }

  #pragma unroll
  for (int i = 0; i < 2; ++i)
    #pragma unroll
    for (int r = 0; r < 4; ++r) {
      int q = qblk * 128 + w * 32 + i * 16 + lg * 4 + r;
      float inv = 1.0f / lrow[i][r];
      #pragma unroll
      for (int jd = 0; jd < 4; ++jd) {
        int c = h * 64 + jd * 16 + lr;
        XO[((size_t)b * 512 + q) * 1024 + c] = (f16)(O[i][jd][r] * inv);
      }
    }
}

// ---------------------------------------------------------------------------
extern "C" void kernel_launch(void* const* d_in, const int* in_sizes, int n_in,
                              void* d_out, int out_size, void* d_ws, size_t ws_size,
                              hipStream_t stream)
{
  (void)in_sizes; (void)n_in; (void)out_size; (void)ws_size;
  const float* x            = (const float*)d_in[0];
  const unsigned char* mask = (const unsigned char*)d_in[1];
  const float* qkv_w   = (const float*)d_in[2];
  const float* qkv_la  = (const float*)d_in[3];
  const float* qkv_lb  = (const float*)d_in[4];
  const float* proj_w  = (const float*)d_in[5];
  const float* proj_b  = (const float*)d_in[6];
  const float* proj_la = (const float*)d_in[7];
  const float* proj_lb = (const float*)d_in[8];
  const float* fc1_w   = (const float*)d_in[9];
  const float* fc1_b   = (const float*)d_in[10];
  const float* fc1_la  = (const float*)d_in[11];
  const float* fc1_lb  = (const float*)d_in[12];
  const float* fc2_w   = (const float*)d_in[13];
  const float* fc2_b   = (const float*)d_in[14];
  const float* fc2_la  = (const float*)d_in[15];
  const float* fc2_lb  = (const float*)d_in[16];
  float* out = (float*)d_out;

  f16* p = (f16*)d_ws;
  f16* WqkvT = p; p += 3072 * 1024;
  f16* W1T   = p; p += 1024 * 1024;
  f16* W2T   = p; p += 1024 * 1024;
  f16* WpT   = p; p += 1024 * 1024;
  f16* Xh    = p; p += 4096 * 1024;
  f16* Qb    = p; p += 128 * 512 * 64;
  f16* Kb    = p; p += 128 * 512 * 64;
  f16* Vt    = p; p += 128 * 64 * 512;
  f16* XO    = p; p += 4096 * 1024;
  unsigned char* cmask = (unsigned char*)p;
  f16* Hb  = Qb;
  f16* XO2 = Xh;

  weff2<<<dim3(12, 16), 256, 0, stream>>>(qkv_w, qkv_la, qkv_lb, WqkvT, 3072, 1024, 1024);
  weff2<<<dim3(4, 16), 256, 0, stream>>>(fc1_w, fc1_la, fc1_lb, W1T, 1024, 1024, 0);
  weff2<<<dim3(4, 16), 256, 0, stream>>>(fc2_w, fc2_la, fc2_lb, W2T, 1024, 1024, 0);
  weff2<<<dim3(4, 16), 256, 0, stream>>>(proj_w, proj_la, proj_lb, WpT, 1024, 1024, 0);
  cvt_f32_f16<<<4096, 256, 0, stream>>>(x, Xh);
  mask_canon<<<1, 256, 0, stream>>>(mask, cmask);

  gemm128<0><<<dim3(32, 24), 256, 0, stream>>>(Xh, WqkvT, 4096, 3072, 1024,
      nullptr, nullptr, nullptr, nullptr, Qb, Kb, Vt);
  attn_kernel<<<dim3(4, 128), 256, 0, stream>>>(Qb, Kb, Vt, cmask, XO);
  gemm128<1><<<dim3(32, 8), 256, 0, stream>>>(XO, W1T, 4096, 1024, 1024,
      fc1_b, nullptr, Hb, nullptr, nullptr, nullptr, nullptr);
  gemm128<2><<<dim3(32, 8), 256, 0, stream>>>(Hb, W2T, 4096, 1024, 1024,
      fc2_b, XO, XO2, nullptr, nullptr, nullptr, nullptr);
  gemm128<3><<<dim3(32, 8), 256, 0, stream>>>(XO2, WpT, 4096, 1024, 1024,
      proj_b, nullptr, nullptr, out, nullptr, nullptr, nullptr);
}

// Round 3
// 314.448 us; speedup vs baseline: 1.6595x; 1.6595x over previous
//
#include <hip/hip_runtime.h>

typedef _Float16 f16;
typedef _Float16 f16x8 __attribute__((ext_vector_type(8)));
typedef _Float16 f16x4v __attribute__((ext_vector_type(4)));
typedef float f32x4 __attribute__((ext_vector_type(4)));

#define DEVINL __device__ __forceinline__

DEVINL void gload16(const void* g, void* l) {
  __builtin_amdgcn_global_load_lds(
      (const __attribute__((address_space(1))) void*)g,
      (__attribute__((address_space(3))) void*)l, 16, 0, 0);
}

// ---------------------------------------------------------------------------
// weff3: WT[n][k] = (W[k][n] + la[k][:]·lb[:][n]) * (n<scaleCols ? 0.125 : 1)
// 64n x 64k tile, 256 threads / 4 waves; wave w owns k-rows w*16..+15, lanes
// own n. la tile in LDS read via wave-uniform broadcast b128 (no scalar
// loads, no conflicts); lb column in 32 VGPRs (coalesced); transpose through
// padded LDS tile -> coalesced f16x8 writes.
// ---------------------------------------------------------------------------
__global__ __launch_bounds__(256) void weff3(
    const float* __restrict__ W, const float* __restrict__ la,
    const float* __restrict__ lb, f16* __restrict__ WT,
    int N, int K, int scaleCols)
{
  __shared__ float La[64][36];   // 144B rows: b128-aligned, broadcast reads
  __shared__ f16 Ts[64][72];     // 144B rows: aligned coalesced read-out
  int t = threadIdx.x;
  int n0 = blockIdx.x * 64, k0 = blockIdx.y * 64;
  int w = t >> 6, nn = t & 63;
  #pragma unroll
  for (int i = 0; i < 8; ++i) {
    int idx = i * 256 + t;
    int row = idx >> 5, r = idx & 31;
    La[row][r] = la[(size_t)(k0 + row) * 32 + r];
  }
  float lbr[32];
  #pragma unroll
  for (int r = 0; r < 32; ++r) lbr[r] = lb[(size_t)r * N + n0 + nn];
  float scale = (n0 + nn < scaleCols) ? 0.125f : 1.0f;
  __syncthreads();
  float prev = 0.0f;
  #pragma unroll
  for (int i = 0; i < 16; ++i) {
    int k = w * 16 + i;
    float acc = W[(size_t)(k0 + k) * N + n0 + nn];
    #pragma unroll
    for (int rc = 0; rc < 8; ++rc) {
      float4 a4 = *(const float4*)&La[k][rc * 4];   // wave-uniform broadcast
      acc += a4.x * lbr[rc * 4] + a4.y * lbr[rc * 4 + 1] +
             a4.z * lbr[rc * 4 + 2] + a4.w * lbr[rc * 4 + 3];
    }
    acc *= scale;
    if (i & 1) {
      union { f16 h[2]; unsigned u; } pk;
      pk.h[0] = (f16)prev; pk.h[1] = (f16)acc;
      *(unsigned*)&Ts[nn][k - 1] = pk.u;
    } else prev = acc;
  }
  __syncthreads();
  #pragma unroll
  for (int it = 0; it < 2; ++it) {
    int id = it * 256 + t;
    int row = id >> 3, c8 = id & 7;
    f16x8 h = *(const f16x8*)&Ts[row][c8 * 8];
    *(f16x8*)(WT + (size_t)(n0 + row) * K + k0 + c8 * 8) = h;
  }
}

// ---------------------------------------------------------------------------
__global__ __launch_bounds__(256) void cvt_f32_f16(const float* __restrict__ in,
                                                   f16* __restrict__ out)
{
  int i = (blockIdx.x * 256 + threadIdx.x) * 4;
  float4 v = *(const float4*)(in + i);
  f16x4v o = {(f16)v.x, (f16)v.y, (f16)v.z, (f16)v.w};
  *(f16x4v*)(out + i) = o;
}

// ---------------------------------------------------------------------------
__global__ __launch_bounds__(256) void mask_canon(const unsigned char* __restrict__ m,
                                                  unsigned char* __restrict__ out)
{
  __shared__ int flag;
  if (threadIdx.x == 0) flag = 0;
  __syncthreads();
  int found = 0;
  for (int p = threadIdx.x; p < 12288; p += 256)
    if ((p & 3) && m[p]) found = 1;
  if (found) flag = 1;
  __syncthreads();
  int u8 = flag;
  const int* mi = (const int*)m;
  for (int idx = threadIdx.x; idx < 4096; idx += 256) {
    int b = idx >> 9, k = idx & 511;
    int v = u8 ? (int)m[b * 1536 + k] : mi[b * 1536 + k];
    out[idx] = (unsigned char)(v != 0);
  }
}

// ---------------------------------------------------------------------------
// 128x128 GEMM, BK=64, 4 waves, mfma_f32_16x16x32_f16, double-buffered LDS
// 2-phase schedule: issue next-tile global_load_lds BEFORE current-tile
// ds_read+MFMA, one __syncthreads (vmcnt drain) per K-step. XOR-swizzled LDS
// via pre-swizzled global source + swizzled ds_read. XCD block remap.
// ---------------------------------------------------------------------------
template <int EPI>
__global__ __launch_bounds__(256) void gemm128(
    const f16* __restrict__ A, const f16* __restrict__ Bt,
    int M, int N, int K,
    const float* __restrict__ bias, const f16* __restrict__ resid,
    f16* __restrict__ outH, float* __restrict__ outF,
    f16* __restrict__ Qo, f16* __restrict__ Ko, f16* __restrict__ Vto)
{
  __shared__ __align__(16) f16 As[2][128 * 64];
  __shared__ __align__(16) f16 Bs[2][128 * 64];
  int tid = threadIdx.x, wid = tid >> 6, l = tid & 63;
  int lg = l >> 4, lr = l & 15;
  int nbx = gridDim.x;
  int nwg = nbx * gridDim.y;
  int flat = blockIdx.y * nbx + blockIdx.x;
  flat = (flat & 7) * (nwg >> 3) + (flat >> 3);
  int bm = (flat % nbx) * 128, bn = (flat / nbx) * 128;
  int wr = (wid >> 1) * 64, wc = (wid & 1) * 64;
  f32x4 acc[4][4] = {};

  int srow = l >> 3, scol = l & 7;
  int sc8 = (scol ^ srow) * 8;
  const f16* gA = A + (size_t)(bm + wid * 32 + srow) * K + sc8;
  const f16* gB = Bt + (size_t)(bn + wid * 32 + srow) * K + sc8;
  int lo = wid * 32 * 64;

  #pragma unroll
  for (int is = 0; is < 4; ++is) {
    gload16(gA + (size_t)(is * 8) * K, As[0] + lo + is * 8 * 64);
    gload16(gB + (size_t)(is * 8) * K, Bs[0] + lo + is * 8 * 64);
  }
  __syncthreads();

  int nt = K >> 6;
  for (int ts = 0; ts < nt; ++ts) {
    int cur = ts & 1, nxt = cur ^ 1;
    if (ts + 1 < nt) {
      int k1 = (ts + 1) << 6;
      #pragma unroll
      for (int is = 0; is < 4; ++is) {
        gload16(gA + (size_t)(is * 8) * K + k1, As[nxt] + lo + is * 8 * 64);
        gload16(gB + (size_t)(is * 8) * K + k1, Bs[nxt] + lo + is * 8 * 64);
      }
    }
    const f16* Ac = As[cur];
    const f16* Bc = Bs[cur];
    f16x8 af[2][4], bf[2][4];
    int x = lr & 7;
    #pragma unroll
    for (int i = 0; i < 4; ++i) {
      int row = wr + i * 16 + lr;
      af[0][i] = *(const f16x8*)(Ac + row * 64 + ((lg ^ x) * 8));
      af[1][i] = *(const f16x8*)(Ac + row * 64 + (((4 + lg) ^ x) * 8));
    }
    #pragma unroll
    for (int j = 0; j < 4; ++j) {
      int row = wc + j * 16 + lr;
      bf[0][j] = *(const f16x8*)(Bc + row * 64 + ((lg ^ x) * 8));
      bf[1][j] = *(const f16x8*)(Bc + row * 64 + (((4 + lg) ^ x) * 8));
    }
    #pragma unroll
    for (int kk = 0; kk < 2; ++kk)
      #pragma unroll
      for (int i = 0; i < 4; ++i)
        #pragma unroll
        for (int j = 0; j < 4; ++j)
          acc[i][j] = __builtin_amdgcn_mfma_f32_16x16x32_f16(af[kk][i], bf[kk][j], acc[i][j], 0, 0, 0);
    __syncthreads();   // drains vmcnt(0): next buffer staged, cur reads done
  }

  #pragma unroll
  for (int i = 0; i < 4; ++i) {
    #pragma unroll
    for (int j = 0; j < 4; ++j) {
      int n = bn + wc + j * 16 + lr;
      float bv = (EPI >= 1) ? bias[n] : 0.0f;
      #pragma unroll
      for (int r = 0; r < 4; ++r) {
        int m = bm + wr + i * 16 + lg * 4 + r;
        float v = acc[i][j][r];
        if (EPI == 0) {
          int bb = m >> 9, ss = m & 511;
          int which = n >> 10, c = n & 1023, hh = c >> 6, dd = c & 63;
          size_t base = (size_t)(bb * 16 + hh);
          if (which == 0)      Qo[(base * 512 + ss) * 64 + dd] = (f16)v;
          else if (which == 1) Ko[(base * 512 + ss) * 64 + dd] = (f16)v;
          else                 Vto[(base * 64 + dd) * 512 + ss] = (f16)v;
        } else if (EPI == 1) {
          v += bv;
          v = 0.5f * v * (1.0f + erff(v * 0.70710678118654752f));
          outH[(size_t)m * N + n] = (f16)v;
        } else if (EPI == 2) {
          v += bv + (float)resid[(size_t)m * N + n];
          outH[(size_t)m * N + n] = (f16)v;
        } else {
          outF[(size_t)m * N + n] = v + bv;
        }
      }
    }
  }
}

// ---------------------------------------------------------------------------
// Flash attention (unchanged from round 2): 4 waves x 32 q-rows, K/V tiles of
// 128 in LDS, XOR-swizzled buffers, XCD remap.
// ---------------------------------------------------------------------------
__global__ __launch_bounds__(256) void attn_kernel(
    const f16* __restrict__ Q, const f16* __restrict__ Kc,
    const f16* __restrict__ Vt, const unsigned char* __restrict__ cmask,
    f16* __restrict__ XO)
{
  __shared__ __align__(16) f16 Ks[128 * 64];
  __shared__ __align__(16) f16 Vs[64 * 128];
  __shared__ __align__(16) f16 Ps[4 * 32 * 128];
  int tid = threadIdx.x, w = tid >> 6, l = tid & 63;
  int lg = l >> 4, lr = l & 15;
  int flat = blockIdx.y * 4 + blockIdx.x;
  flat = (flat & 7) * 64 + (flat >> 3);
  int qblk = flat & 3, bh = flat >> 2;
  int b = bh >> 4, h = bh & 15;
  const f16* Qg = Q + (size_t)bh * 512 * 64 + qblk * 128 * 64;
  const f16* Kg = Kc + (size_t)bh * 512 * 64;
  const f16* Vg = Vt + (size_t)bh * 64 * 512;
  const unsigned char* mb = cmask + b * 512;

  f16x8 qf[2][2];
  #pragma unroll
  for (int i = 0; i < 2; ++i)
    #pragma unroll
    for (int kc = 0; kc < 2; ++kc)
      qf[i][kc] = *(const f16x8*)(Qg + (size_t)(w * 32 + i * 16 + lr) * 64 + kc * 32 + lg * 8);

  f32x4 O[2][4] = {};
  float mrow[2][4], lrow[2][4];
  #pragma unroll
  for (int i = 0; i < 2; ++i)
    #pragma unroll
    for (int r = 0; r < 4; ++r) { mrow[i][r] = -1e30f; lrow[i][r] = 0.0f; }

  f16* Pw = Ps + w * 32 * 128;
  int ksrow = l >> 3;
  int ksc = ((l & 7) ^ ksrow) * 8;
  int vrow = l >> 4;
  int v7 = (w * 4 + vrow) & 7;
  int vsc = ((l & 15) ^ v7) * 8;

  for (int kt = 0; kt < 4; ++kt) {
    __syncthreads();
    #pragma unroll
    for (int is = 0; is < 4; ++is)
      gload16(Kg + (size_t)(kt * 128 + is * 32 + w * 8 + ksrow) * 64 + ksc,
              Ks + (is * 32 + w * 8) * 64);
    #pragma unroll
    for (int is = 0; is < 4; ++is)
      gload16(Vg + (size_t)(is * 16 + w * 4 + vrow) * 512 + kt * 128 + vsc,
              Vs + (is * 16 + w * 4) * 128);
    __syncthreads();

    int x = lr & 7;
    f32x4 sc[2][8] = {};
    #pragma unroll
    for (int j = 0; j < 8; ++j) {
      const f16* krow = Ks + (j * 16 + lr) * 64;
      f16x8 kf0 = *(const f16x8*)(krow + ((lg ^ x) * 8));
      f16x8 kf1 = *(const f16x8*)(krow + (((4 + lg) ^ x) * 8));
      sc[0][j] = __builtin_amdgcn_mfma_f32_16x16x32_f16(qf[0][0], kf0, sc[0][j], 0, 0, 0);
      sc[0][j] = __builtin_amdgcn_mfma_f32_16x16x32_f16(qf[0][1], kf1, sc[0][j], 0, 0, 0);
      sc[1][j] = __builtin_amdgcn_mfma_f32_16x16x32_f16(qf[1][0], kf0, sc[1][j], 0, 0, 0);
      sc[1][j] = __builtin_amdgcn_mfma_f32_16x16x32_f16(qf[1][1], kf1, sc[1][j], 0, 0, 0);
    }
    bool keep[8];
    #pragma unroll
    for (int j = 0; j < 8; ++j) keep[j] = mb[kt * 128 + j * 16 + lr] != 0;
    #pragma unroll
    for (int i = 0; i < 2; ++i)
      #pragma unroll
      for (int j = 0; j < 8; ++j)
        #pragma unroll
        for (int r = 0; r < 4; ++r)
          sc[i][j][r] = keep[j] ? sc[i][j][r] : -1e30f;

    #pragma unroll
    for (int i = 0; i < 2; ++i) {
      #pragma unroll
      for (int r = 0; r < 4; ++r) {
        float pm = sc[i][0][r];
        #pragma unroll
        for (int j = 1; j < 8; ++j) pm = fmaxf(pm, sc[i][j][r]);
        pm = fmaxf(pm, __shfl_xor(pm, 1));
        pm = fmaxf(pm, __shfl_xor(pm, 2));
        pm = fmaxf(pm, __shfl_xor(pm, 4));
        pm = fmaxf(pm, __shfl_xor(pm, 8));
        float mn = fmaxf(mrow[i][r], pm);
        float alpha = __expf(mrow[i][r] - mn);
        mrow[i][r] = mn;
        lrow[i][r] *= alpha;
        #pragma unroll
        for (int jd = 0; jd < 4; ++jd) O[i][jd][r] *= alpha;
      }
    }
    #pragma unroll
    for (int i = 0; i < 2; ++i) {
      float rs[4] = {0.f, 0.f, 0.f, 0.f};
      #pragma unroll
      for (int j = 0; j < 8; ++j)
        #pragma unroll
        for (int r = 0; r < 4; ++r) {
          float p = __expf(sc[i][j][r] - mrow[i][r]);
          rs[r] += p;
          int prow = i * 16 + lg * 4 + r;
          int pc = j * 16 + lr;
          Pw[prow * 128 + ((((pc >> 3) ^ (prow & 7)) << 3) | (pc & 7))] = (f16)p;
        }
      #pragma unroll
      for (int r = 0; r < 4; ++r) {
        float s = rs[r];
        s += __shfl_xor(s, 1); s += __shfl_xor(s, 2);
        s += __shfl_xor(s, 4); s += __shfl_xor(s, 8);
        lrow[i][r] += s;
      }
    }
    #pragma unroll
    for (int kk = 0; kk < 4; ++kk) {
      int c0 = ((kk * 4 + lg) ^ x) * 8;
      f16x8 pa0 = *(const f16x8*)(Pw + lr * 128 + c0);
      f16x8 pa1 = *(const f16x8*)(Pw + (16 + lr) * 128 + c0);
      #pragma unroll
      for (int jd = 0; jd < 4; ++jd) {
        f16x8 vb = *(const f16x8*)(Vs + (jd * 16 + lr) * 128 + c0);
        O[0][jd] = __builtin_amdgcn_mfma_f32_16x16x32_f16(pa0, vb, O[0][jd], 0, 0, 0);
        O[1][jd] = __builtin_amdgcn_mfma_f32_16x16x32_f16(pa1, vb, O[1][jd], 0, 0, 0);
      }
    }
  }

  #pragma unroll
  for (int i = 0; i < 2; ++i)
    #pragma unroll
    for (int r = 0; r < 4; ++r) {
      int q = qblk * 128 + w * 32 + i * 16 + lg * 4 + r;
      float inv = 1.0f / lrow[i][r];
      #pragma unroll
      for (int jd = 0; jd < 4; ++jd) {
        int c = h * 64 + jd * 16 + lr;
        XO[((size_t)b * 512 + q) * 1024 + c] = (f16)(O[i][jd][r] * inv);
      }
    }
}

// ---------------------------------------------------------------------------
extern "C" void kernel_launch(void* const* d_in, const int* in_sizes, int n_in,
                              void* d_out, int out_size, void* d_ws, size_t ws_size,
                              hipStream_t stream)
{
  (void)in_sizes; (void)n_in; (void)out_size; (void)ws_size;
  const float* x            = (const float*)d_in[0];
  const unsigned char* mask = (const unsigned char*)d_in[1];
  const float* qkv_w   = (const float*)d_in[2];
  const float* qkv_la  = (const float*)d_in[3];
  const float* qkv_lb  = (const float*)d_in[4];
  const float* proj_w  = (const float*)d_in[5];
  const float* proj_b  = (const float*)d_in[6];
  const float* proj_la = (const float*)d_in[7];
  const float* proj_lb = (const float*)d_in[8];
  const float* fc1_w   = (const float*)d_in[9];
  const float* fc1_b   = (const float*)d_in[10];
  const float* fc1_la  = (const float*)d_in[11];
  const float* fc1_lb  = (const float*)d_in[12];
  const float* fc2_w   = (const float*)d_in[13];
  const float* fc2_b   = (const float*)d_in[14];
  const float* fc2_la  = (const float*)d_in[15];
  const float* fc2_lb  = (const float*)d_in[16];
  float* out = (float*)d_out;

  f16* p = (f16*)d_ws;
  f16* WqkvT = p; p += 3072 * 1024;
  f16* W1T   = p; p += 1024 * 1024;
  f16* W2T   = p; p += 1024 * 1024;
  f16* WpT   = p; p += 1024 * 1024;
  f16* Xh    = p; p += 4096 * 1024;
  f16* Qb    = p; p += 128 * 512 * 64;
  f16* Kb    = p; p += 128 * 512 * 64;
  f16* Vt    = p; p += 128 * 64 * 512;
  f16* XO    = p; p += 4096 * 1024;
  unsigned char* cmask = (unsigned char*)p;
  f16* Hb  = Qb;
  f16* XO2 = Xh;

  weff3<<<dim3(48, 16), 256, 0, stream>>>(qkv_w, qkv_la, qkv_lb, WqkvT, 3072, 1024, 1024);
  weff3<<<dim3(16, 16), 256, 0, stream>>>(fc1_w, fc1_la, fc1_lb, W1T, 1024, 1024, 0);
  weff3<<<dim3(16, 16), 256, 0, stream>>>(fc2_w, fc2_la, fc2_lb, W2T, 1024, 1024, 0);
  weff3<<<dim3(16, 16), 256, 0, stream>>>(proj_w, proj_la, proj_lb, WpT, 1024, 1024, 0);
  cvt_f32_f16<<<4096, 256, 0, stream>>>(x, Xh);
  mask_canon<<<1, 256, 0, stream>>>(mask, cmask);

  gemm128<0><<<dim3(32, 24), 256, 0, stream>>>(Xh, WqkvT, 4096, 3072, 1024,
      nullptr, nullptr, nullptr, nullptr, Qb, Kb, Vt);
  attn_kernel<<<dim3(4, 128), 256, 0, stream>>>(Qb, Kb, Vt, cmask, XO);
  gemm128<1><<<dim3(32, 8), 256, 0, stream>>>(XO, W1T, 4096, 1024, 1024,
      fc1_b, nullptr, Hb, nullptr, nullptr, nullptr, nullptr);
  gemm128<2><<<dim3(32, 8), 256, 0, stream>>>(Hb, W2T, 4096, 1024, 1024,
      fc2_b, XO, XO2, nullptr, nullptr, nullptr, nullptr);
  gemm128<3><<<dim3(32, 8), 256, 0, stream>>>(XO2, WpT, 4096, 1024, 1024,
      proj_b, nullptr, nullptr, out, nullptr, nullptr, nullptr);
}

// Round 4
// 283.042 us; speedup vs baseline: 1.8437x; 1.1110x over previous
//
#include <hip/hip_runtime.h>

typedef _Float16 f16;
typedef _Float16 f16x8 __attribute__((ext_vector_type(8)));
typedef _Float16 f16x4v __attribute__((ext_vector_type(4)));
typedef float f32x4 __attribute__((ext_vector_type(4)));

#define DEVINL __device__ __forceinline__

DEVINL void gload16(const void* g, void* l) {
  __builtin_amdgcn_global_load_lds(
      (const __attribute__((address_space(1))) void*)g,
      (__attribute__((address_space(3))) void*)l, 16, 0, 0);
}

// ---------------------------------------------------------------------------
// weff3 (unchanged): WT[n][k] = (W[k][n] + la[k][:]·lb[:][n]) * scale
// ---------------------------------------------------------------------------
__global__ __launch_bounds__(256) void weff3(
    const float* __restrict__ W, const float* __restrict__ la,
    const float* __restrict__ lb, f16* __restrict__ WT,
    int N, int K, int scaleCols)
{
  __shared__ float La[64][36];
  __shared__ f16 Ts[64][72];
  int t = threadIdx.x;
  int n0 = blockIdx.x * 64, k0 = blockIdx.y * 64;
  int w = t >> 6, nn = t & 63;
  #pragma unroll
  for (int i = 0; i < 8; ++i) {
    int idx = i * 256 + t;
    int row = idx >> 5, r = idx & 31;
    La[row][r] = la[(size_t)(k0 + row) * 32 + r];
  }
  float lbr[32];
  #pragma unroll
  for (int r = 0; r < 32; ++r) lbr[r] = lb[(size_t)r * N + n0 + nn];
  float scale = (n0 + nn < scaleCols) ? 0.125f : 1.0f;
  __syncthreads();
  float prev = 0.0f;
  #pragma unroll
  for (int i = 0; i < 16; ++i) {
    int k = w * 16 + i;
    float acc = W[(size_t)(k0 + k) * N + n0 + nn];
    #pragma unroll
    for (int rc = 0; rc < 8; ++rc) {
      float4 a4 = *(const float4*)&La[k][rc * 4];
      acc += a4.x * lbr[rc * 4] + a4.y * lbr[rc * 4 + 1] +
             a4.z * lbr[rc * 4 + 2] + a4.w * lbr[rc * 4 + 3];
    }
    acc *= scale;
    if (i & 1) {
      union { f16 h[2]; unsigned u; } pk;
      pk.h[0] = (f16)prev; pk.h[1] = (f16)acc;
      *(unsigned*)&Ts[nn][k - 1] = pk.u;
    } else prev = acc;
  }
  __syncthreads();
  #pragma unroll
  for (int it = 0; it < 2; ++it) {
    int id = it * 256 + t;
    int row = id >> 3, c8 = id & 7;
    f16x8 h = *(const f16x8*)&Ts[row][c8 * 8];
    *(f16x8*)(WT + (size_t)(n0 + row) * K + k0 + c8 * 8) = h;
  }
}

// ---------------------------------------------------------------------------
__global__ __launch_bounds__(256) void cvt_f32_f16(const float* __restrict__ in,
                                                   f16* __restrict__ out)
{
  int i = (blockIdx.x * 256 + threadIdx.x) * 4;
  float4 v = *(const float4*)(in + i);
  f16x4v o = {(f16)v.x, (f16)v.y, (f16)v.z, (f16)v.w};
  *(f16x4v*)(out + i) = o;
}

// ---------------------------------------------------------------------------
__global__ __launch_bounds__(256) void mask_canon(const unsigned char* __restrict__ m,
                                                  unsigned char* __restrict__ out)
{
  __shared__ int flag;
  if (threadIdx.x == 0) flag = 0;
  __syncthreads();
  int found = 0;
  for (int p = threadIdx.x; p < 12288; p += 256)
    if ((p & 3) && m[p]) found = 1;
  if (found) flag = 1;
  __syncthreads();
  int u8 = flag;
  const int* mi = (const int*)m;
  for (int idx = threadIdx.x; idx < 4096; idx += 256) {
    int b = idx >> 9, k = idx & 511;
    int v = u8 ? (int)m[b * 1536 + k] : mi[b * 1536 + k];
    out[idx] = (unsigned char)(v != 0);
  }
}

// ---------------------------------------------------------------------------
// GEMM, tile BM x 128, BK=32, double-buffered (2x(BM+128)x32x2B LDS),
// 4 waves (2x2), mfma_f32_16x16x32_f16. 64B LDS rows, swizzle
// chunk ^= (row>>1)&3 (frag reads become 8-lane broadcasts, conflict-free);
// source pre-swizzle (l&3)^((l>>3)&3) is the matching involution.
// XCD remap: each XCD owns a contiguous bm-stripe (A L2-resident, B streams).
// ---------------------------------------------------------------------------
template <int EPI, int BM>
__global__ __launch_bounds__(256, 3) void gemmk(
    const f16* __restrict__ A, const f16* __restrict__ Bt,
    int M, int N, int K,
    const float* __restrict__ bias, const f16* __restrict__ resid,
    f16* __restrict__ outH, float* __restrict__ outF,
    f16* __restrict__ Qo, f16* __restrict__ Ko, f16* __restrict__ Vto)
{
  constexpr int MF = BM / 32;           // m-frags per wave
  __shared__ __align__(16) f16 As[2][BM * 32];
  __shared__ __align__(16) f16 Bs[2][128 * 32];
  int tid = threadIdx.x, wid = tid >> 6, l = tid & 63;
  int lg = l >> 4, lr = l & 15;
  int nbx = gridDim.x;
  int flat = blockIdx.y * nbx + blockIdx.x;
  int xcd = flat & 7, idx = flat >> 3;
  int mc = nbx >> 3;                    // bm tiles per XCD stripe
  int bm = (xcd * mc + idx % mc) * BM;
  int bn = (idx / mc) * 128;
  int wr = (wid >> 1) * (BM / 2), wc = (wid & 1) * 64;
  f32x4 acc[MF][4] = {};

  int swz = ((l & 3) ^ ((l >> 3) & 3)) * 8;   // source chunk involution
  const f16* gA = A + (size_t)(bm + wid * (BM / 4) + (l >> 2)) * K + swz;
  const f16* gB = Bt + (size_t)(bn + wid * 32 + (l >> 2)) * K + swz;
  int xr = (lr >> 1) & 3;                     // read-side XOR

  // prologue: stage tile 0
  #pragma unroll
  for (int ig = 0; ig < BM / 64; ++ig)
    gload16(gA + (size_t)(ig * 16) * K, As[0] + (wid * (BM / 4) + ig * 16) * 32);
  #pragma unroll
  for (int ig = 0; ig < 2; ++ig)
    gload16(gB + (size_t)(ig * 16) * K, Bs[0] + (wid * 32 + ig * 16) * 32);
  __syncthreads();

  int nt = K >> 5;
  for (int ts = 0; ts < nt; ++ts) {
    int cur = ts & 1, nxt = cur ^ 1;
    if (ts + 1 < nt) {
      int k1 = (ts + 1) << 5;
      #pragma unroll
      for (int ig = 0; ig < BM / 64; ++ig)
        gload16(gA + (size_t)(ig * 16) * K + k1, As[nxt] + (wid * (BM / 4) + ig * 16) * 32);
      #pragma unroll
      for (int ig = 0; ig < 2; ++ig)
        gload16(gB + (size_t)(ig * 16) * K + k1, Bs[nxt] + (wid * 32 + ig * 16) * 32);
    }
    const f16* Ac = As[cur];
    const f16* Bc = Bs[cur];
    f16x8 bf[4];
    #pragma unroll
    for (int j = 0; j < 4; ++j) {
      int row = wc + j * 16 + lr;
      bf[j] = *(const f16x8*)(Bc + row * 32 + ((lg ^ xr) * 8));
    }
    __builtin_amdgcn_s_setprio(1);
    #pragma unroll
    for (int i = 0; i < MF; ++i) {
      int row = wr + i * 16 + lr;
      f16x8 af = *(const f16x8*)(Ac + row * 32 + ((lg ^ xr) * 8));
      #pragma unroll
      for (int j = 0; j < 4; ++j)
        acc[i][j] = __builtin_amdgcn_mfma_f32_16x16x32_f16(af, bf[j], acc[i][j], 0, 0, 0);
    }
    __builtin_amdgcn_s_setprio(0);
    __syncthreads();   // vmcnt(0)+lgkmcnt(0) drain + barrier: next tile ready
  }

  #pragma unroll
  for (int i = 0; i < MF; ++i) {
    #pragma unroll
    for (int j = 0; j < 4; ++j) {
      int n = bn + wc + j * 16 + lr;
      float bv = (EPI >= 1) ? bias[n] : 0.0f;
      #pragma unroll
      for (int r = 0; r < 4; ++r) {
        int m = bm + wr + i * 16 + lg * 4 + r;
        float v = acc[i][j][r];
        if (EPI == 0) {
          int bb = m >> 9, ss = m & 511;
          int which = n >> 10, c = n & 1023, hh = c >> 6, dd = c & 63;
          size_t base = (size_t)(bb * 16 + hh);
          if (which == 0)      Qo[(base * 512 + ss) * 64 + dd] = (f16)v;
          else if (which == 1) Ko[(base * 512 + ss) * 64 + dd] = (f16)v;
          else                 Vto[(base * 64 + dd) * 512 + ss] = (f16)v;
        } else if (EPI == 1) {
          v += bv;
          v = 0.5f * v * (1.0f + erff(v * 0.70710678118654752f));
          outH[(size_t)m * N + n] = (f16)v;
        } else if (EPI == 2) {
          v += bv + (float)resid[(size_t)m * N + n];
          outH[(size_t)m * N + n] = (f16)v;
        } else {
          outF[(size_t)m * N + n] = v + bv;
        }
      }
    }
  }
}

// ---------------------------------------------------------------------------
// Flash attention, 4 waves x 32 q-rows, K/V tiles of 128.
// T14 reg-staging: global->VGPR issued before the compute phase (latency
// hides under QK/softmax/PV), ds_write (swizzled dest) after the barrier.
// ---------------------------------------------------------------------------
__global__ __launch_bounds__(256, 2) void attn_kernel(
    const f16* __restrict__ Q, const f16* __restrict__ Kc,
    const f16* __restrict__ Vt, const unsigned char* __restrict__ cmask,
    f16* __restrict__ XO)
{
  __shared__ __align__(16) f16 Ks[128 * 64];     // [krow][d] 128B rows
  __shared__ __align__(16) f16 Vs[64 * 128];     // [d][krow] 256B rows
  __shared__ __align__(16) f16 Ps[4 * 32 * 128];
  int tid = threadIdx.x, w = tid >> 6, l = tid & 63;
  int lg = l >> 4, lr = l & 15;
  int flat = blockIdx.y * 4 + blockIdx.x;
  flat = (flat & 7) * 64 + (flat >> 3);
  int qblk = flat & 3, bh = flat >> 2;
  int b = bh >> 4, h = bh & 15;
  const f16* Qg = Q + (size_t)bh * 512 * 64 + qblk * 128 * 64;
  const f16* Kg = Kc + (size_t)bh * 512 * 64;
  const f16* Vg = Vt + (size_t)bh * 64 * 512;
  const unsigned char* mb = cmask + b * 512;

  f16x8 qf[2][2];
  #pragma unroll
  for (int i = 0; i < 2; ++i)
    #pragma unroll
    for (int kc = 0; kc < 2; ++kc)
      qf[i][kc] = *(const f16x8*)(Qg + (size_t)(w * 32 + i * 16 + lr) * 64 + kc * 32 + lg * 8);

  f32x4 O[2][4] = {};
  float mrow[2][4], lrow[2][4];
  #pragma unroll
  for (int i = 0; i < 2; ++i)
    #pragma unroll
    for (int r = 0; r < 4; ++r) { mrow[i][r] = -1e30f; lrow[i][r] = 0.0f; }

  f16* Pw = Ps + w * 32 * 128;

  // reg-staging lane mapping
  int kR = tid >> 3, kC = (tid & 7) * 8;     // K: 32 rows/iter, 128B rows
  int vR = tid >> 4, vC = (tid & 15) * 8;    // V: 16 rows/iter, 256B rows
  f16x8 kreg[4], vreg[4];
  #pragma unroll
  for (int i = 0; i < 4; ++i) {
    kreg[i] = *(const f16x8*)(Kg + (size_t)(i * 32 + kR) * 64 + kC);
    vreg[i] = *(const f16x8*)(Vg + (size_t)(i * 16 + vR) * 512 + vC);
  }

  for (int kt = 0; kt < 4; ++kt) {
    // write staged regs to LDS with swizzled dest (content(c')=global(c'^row&7))
    #pragma unroll
    for (int i = 0; i < 4; ++i) {
      int krow = i * 32 + kR;
      *(f16x8*)(Ks + krow * 64 + (((tid & 7) ^ (krow & 7)) * 8)) = kreg[i];
      int vrow = i * 16 + vR;
      *(f16x8*)(Vs + vrow * 128 + (((tid & 15) ^ (vrow & 7)) * 8)) = vreg[i];
    }
    __syncthreads();
    if (kt < 3) {   // issue next-tile loads; land during compute (T14)
      #pragma unroll
      for (int i = 0; i < 4; ++i) {
        kreg[i] = *(const f16x8*)(Kg + (size_t)((kt + 1) * 128 + i * 32 + kR) * 64 + kC);
        vreg[i] = *(const f16x8*)(Vg + (size_t)(i * 16 + vR) * 512 + (kt + 1) * 128 + vC);
      }
    }

    int x = lr & 7;
    f32x4 sc[2][8] = {};
    __builtin_amdgcn_s_setprio(1);
    #pragma unroll
    for (int j = 0; j < 8; ++j) {
      const f16* krow = Ks + (j * 16 + lr) * 64;
      f16x8 kf0 = *(const f16x8*)(krow + ((lg ^ x) * 8));
      f16x8 kf1 = *(const f16x8*)(krow + (((4 + lg) ^ x) * 8));
      sc[0][j] = __builtin_amdgcn_mfma_f32_16x16x32_f16(qf[0][0], kf0, sc[0][j], 0, 0, 0);
      sc[0][j] = __builtin_amdgcn_mfma_f32_16x16x32_f16(qf[0][1], kf1, sc[0][j], 0, 0, 0);
      sc[1][j] = __builtin_amdgcn_mfma_f32_16x16x32_f16(qf[1][0], kf0, sc[1][j], 0, 0, 0);
      sc[1][j] = __builtin_amdgcn_mfma_f32_16x16x32_f16(qf[1][1], kf1, sc[1][j], 0, 0, 0);
    }
    __builtin_amdgcn_s_setprio(0);
    bool keep[8];
    #pragma unroll
    for (int j = 0; j < 8; ++j) keep[j] = mb[kt * 128 + j * 16 + lr] != 0;
    #pragma unroll
    for (int i = 0; i < 2; ++i)
      #pragma unroll
      for (int j = 0; j < 8; ++j)
        #pragma unroll
        for (int r = 0; r < 4; ++r)
          sc[i][j][r] = keep[j] ? sc[i][j][r] : -1e30f;

    #pragma unroll
    for (int i = 0; i < 2; ++i) {
      #pragma unroll
      for (int r = 0; r < 4; ++r) {
        float pm = sc[i][0][r];
        #pragma unroll
        for (int j = 1; j < 8; ++j) pm = fmaxf(pm, sc[i][j][r]);
        pm = fmaxf(pm, __shfl_xor(pm, 1));
        pm = fmaxf(pm, __shfl_xor(pm, 2));
        pm = fmaxf(pm, __shfl_xor(pm, 4));
        pm = fmaxf(pm, __shfl_xor(pm, 8));
        float mn = fmaxf(mrow[i][r], pm);
        float alpha = __expf(mrow[i][r] - mn);
        mrow[i][r] = mn;
        lrow[i][r] *= alpha;
        #pragma unroll
        for (int jd = 0; jd < 4; ++jd) O[i][jd][r] *= alpha;
      }
    }
    #pragma unroll
    for (int i = 0; i < 2; ++i) {
      float rs[4] = {0.f, 0.f, 0.f, 0.f};
      #pragma unroll
      for (int j = 0; j < 8; ++j)
        #pragma unroll
        for (int r = 0; r < 4; ++r) {
          float p = __expf(sc[i][j][r] - mrow[i][r]);
          rs[r] += p;
          int prow = i * 16 + lg * 4 + r;
          int pc = j * 16 + lr;
          Pw[prow * 128 + ((((pc >> 3) ^ (prow & 7)) << 3) | (pc & 7))] = (f16)p;
        }
      #pragma unroll
      for (int r = 0; r < 4; ++r) {
        float s = rs[r];
        s += __shfl_xor(s, 1); s += __shfl_xor(s, 2);
        s += __shfl_xor(s, 4); s += __shfl_xor(s, 8);
        lrow[i][r] += s;
      }
    }
    __builtin_amdgcn_s_setprio(1);
    #pragma unroll
    for (int kk = 0; kk < 4; ++kk) {
      int c0 = ((kk * 4 + lg) ^ x) * 8;
      f16x8 pa0 = *(const f16x8*)(Pw + lr * 128 + c0);
      f16x8 pa1 = *(const f16x8*)(Pw + (16 + lr) * 128 + c0);
      #pragma unroll
      for (int jd = 0; jd < 4; ++jd) {
        f16x8 vb = *(const f16x8*)(Vs + (jd * 16 + lr) * 128 + c0);
        O[0][jd] = __builtin_amdgcn_mfma_f32_16x16x32_f16(pa0, vb, O[0][jd], 0, 0, 0);
        O[1][jd] = __builtin_amdgcn_mfma_f32_16x16x32_f16(pa1, vb, O[1][jd], 0, 0, 0);
      }
    }
    __builtin_amdgcn_s_setprio(0);
    __syncthreads();   // all waves done reading Ks/Vs before next ds_write
  }

  #pragma unroll
  for (int i = 0; i < 2; ++i)
    #pragma unroll
    for (int r = 0; r < 4; ++r) {
      int q = qblk * 128 + w * 32 + i * 16 + lg * 4 + r;
      float inv = 1.0f / lrow[i][r];
      #pragma unroll
      for (int jd = 0; jd < 4; ++jd) {
        int c = h * 64 + jd * 16 + lr;
        XO[((size_t)b * 512 + q) * 1024 + c] = (f16)(O[i][jd][r] * inv);
      }
    }
}

// ---------------------------------------------------------------------------
extern "C" void kernel_launch(void* const* d_in, const int* in_sizes, int n_in,
                              void* d_out, int out_size, void* d_ws, size_t ws_size,
                              hipStream_t stream)
{
  (void)in_sizes; (void)n_in; (void)out_size; (void)ws_size;
  const float* x            = (const float*)d_in[0];
  const unsigned char* mask = (const unsigned char*)d_in[1];
  const float* qkv_w   = (const float*)d_in[2];
  const float* qkv_la  = (const float*)d_in[3];
  const float* qkv_lb  = (const float*)d_in[4];
  const float* proj_w  = (const float*)d_in[5];
  const float* proj_b  = (const float*)d_in[6];
  const float* proj_la = (const float*)d_in[7];
  const float* proj_lb = (const float*)d_in[8];
  const float* fc1_w   = (const float*)d_in[9];
  const float* fc1_b   = (const float*)d_in[10];
  const float* fc1_la  = (const float*)d_in[11];
  const float* fc1_lb  = (const float*)d_in[12];
  const float* fc2_w   = (const float*)d_in[13];
  const float* fc2_b   = (const float*)d_in[14];
  const float* fc2_la  = (const float*)d_in[15];
  const float* fc2_lb  = (const float*)d_in[16];
  float* out = (float*)d_out;

  f16* p = (f16*)d_ws;
  f16* WqkvT = p; p += 3072 * 1024;
  f16* W1T   = p; p += 1024 * 1024;
  f16* W2T   = p; p += 1024 * 1024;
  f16* WpT   = p; p += 1024 * 1024;
  f16* Xh    = p; p += 4096 * 1024;
  f16* Qb    = p; p += 128 * 512 * 64;
  f16* Kb    = p; p += 128 * 512 * 64;
  f16* Vt    = p; p += 128 * 64 * 512;
  f16* XO    = p; p += 4096 * 1024;
  unsigned char* cmask = (unsigned char*)p;
  f16* Hb  = Qb;
  f16* XO2 = Xh;

  weff3<<<dim3(48, 16), 256, 0, stream>>>(qkv_w, qkv_la, qkv_lb, WqkvT, 3072, 1024, 1024);
  weff3<<<dim3(16, 16), 256, 0, stream>>>(fc1_w, fc1_la, fc1_lb, W1T, 1024, 1024, 0);
  weff3<<<dim3(16, 16), 256, 0, stream>>>(fc2_w, fc2_la, fc2_lb, W2T, 1024, 1024, 0);
  weff3<<<dim3(16, 16), 256, 0, stream>>>(proj_w, proj_la, proj_lb, WpT, 1024, 1024, 0);
  cvt_f32_f16<<<4096, 256, 0, stream>>>(x, Xh);
  mask_canon<<<1, 256, 0, stream>>>(mask, cmask);

  gemmk<0, 128><<<dim3(32, 24), 256, 0, stream>>>(Xh, WqkvT, 4096, 3072, 1024,
      nullptr, nullptr, nullptr, nullptr, Qb, Kb, Vt);
  attn_kernel<<<dim3(4, 128), 256, 0, stream>>>(Qb, Kb, Vt, cmask, XO);
  gemmk<1, 64><<<dim3(64, 8), 256, 0, stream>>>(XO, W1T, 4096, 1024, 1024,
      fc1_b, nullptr, Hb, nullptr, nullptr, nullptr, nullptr);
  gemmk<2, 64><<<dim3(64, 8), 256, 0, stream>>>(Hb, W2T, 4096, 1024, 1024,
      fc2_b, XO, XO2, nullptr, nullptr, nullptr, nullptr);
  gemmk<3, 64><<<dim3(64, 8), 256, 0, stream>>>(XO2, WpT, 4096, 1024, 1024,
      proj_b, nullptr, nullptr, out, nullptr, nullptr, nullptr);
}